// Round 7
// baseline (645.839 us; speedup 1.0000x reference)
//
#include <hip/hip_runtime.h>

typedef _Float16 half8 __attribute__((ext_vector_type(8)));
typedef float floatx16 __attribute__((ext_vector_type(16)));

// x[16,3,32,128,128] f32 -> Conv3d(3->24,k=3,VALID) -> +bias -> min over depth -> softmax(co)
// out [16,24,1,126,126] f32
//
// v_mfma_f32_32x32x16_f16: M=32 w, N=32 (24 co), K=16 packed k=ci*4+kh' (12 used).
// One staged slab (4 h-rows) serves TWO output h values (delta=0,1) via two B-tables.
// C/D layout self-calibrated in prep (probe MFMAs -> u16 idx table in ws).

#define WS_IDX_OFF 0      // 2048 B: u16 idx[16][64] = wm*32+cm
#define WS_BF_OFF  2048   // 18432 B: half8 Bf[2][3][3][64]

__global__ void ModelNew_80908593922715_prep(const float* __restrict__ wt,
                                             void* __restrict__ ws)
{
    const int lane = threadIdx.x;            // 0..63
    const int co = lane & 31, q = lane >> 5;
    const int b  = blockIdx.x;               // 0..17 = (delta*9 + kd*3 + kw)
    const int dlt = b / 9;
    const int kd = (b % 9) / 3, kw = b % 3;

    half8 bf;
    #pragma unroll
    for (int j = 0; j < 8; ++j) {
        int k = q*8 + j;                     // k = ci*4 + kh'
        int ci = k >> 2, khp = k & 3;
        int kh = khp - dlt;                  // weight kh tap
        float wv = 0.0f;
        if (co < 24 && ci < 3 && kh >= 0 && kh < 3)
            wv = wt[co*81 + ci*27 + kd*9 + kh*3 + kw];
        bf[j] = (_Float16)wv;
    }
    *(half8*)((char*)ws + WS_BF_OFF + (size_t)(b*64 + lane)*16) = bf;

    if (b == 0) {
        // probe ACTUAL C/D layout: dwp = 16*row(w), dcp = 16*col(co)
        half8 pa, pone;
        #pragma unroll
        for (int j = 0; j < 8; ++j) { pa[j] = (_Float16)(float)co; pone[j] = (_Float16)1.0f; }
        floatx16 dwp{}, dcp{};
        dwp = __builtin_amdgcn_mfma_f32_32x32x16_f16(pa,   pone, dwp, 0, 0, 0);
        dcp = __builtin_amdgcn_mfma_f32_32x32x16_f16(pone, pa,   dcp, 0, 0, 0);
        unsigned short* idx = (unsigned short*)((char*)ws + WS_IDX_OFF);
        #pragma unroll
        for (int r = 0; r < 16; ++r) {
            int wm = (int)(dwp[r] * 0.0625f + 0.5f);
            int cm = (int)(dcp[r] * 0.0625f + 0.5f);
            idx[r*64 + lane] = (unsigned short)(wm*32 + cm);
        }
    }
}

__global__ __launch_bounds__(512, 6)
void ModelNew_80908593922715_kernel(const float* __restrict__ x,
                                    const float* __restrict__ bias,
                                    const void* __restrict__ ws,
                                    float* __restrict__ out)
{
    __shared__ __align__(16) _Float16 XT[26112]; // 1088 rows (dd*34+w2) x 48 B

    const int tid  = threadIdx.x;
    const int lane = tid & 63;
    const int wid  = tid >> 6;
    const int q    = lane >> 5;

    // ---- bijective XCD swizzle over 4032 blocks (8 XCDs x 504)
    const int bid = blockIdx.y * 252 + blockIdx.x;
    const int logical = (bid & 7) * 504 + (bid >> 3);
    const int n  = logical / 252;
    const int lx = logical % 252;
    const int hp = lx >> 2;          // 0..62 -> h0 = 2*hp
    const int wq = lx & 3;
    const int h0 = hp * 2;
    const int W0 = wq * 32;

    // ---- constants from ws (L2-resident)
    const char* wsB = (const char*)ws + WS_BF_OFF;
    half8 Bf0[3][3], Bf1[3][3];
    #pragma unroll
    for (int kd = 0; kd < 3; ++kd)
      #pragma unroll
      for (int kw = 0; kw < 3; ++kw) {
        Bf0[kd][kw] = *(const half8*)(wsB + (size_t)(((0*9 + kd*3+kw)*64) + lane)*16);
        Bf1[kd][kw] = *(const half8*)(wsB + (size_t)(((1*9 + kd*3+kw)*64) + lane)*16);
      }

    const unsigned short* idxT = (const unsigned short*)((const char*)ws + WS_IDX_OFF);
    const unsigned short ic0 = idxT[(wid*2 + 0)*64 + lane];
    const unsigned short ic1 = idxT[(wid*2 + 1)*64 + lane];
    float bco = 0.0f;
    if ((lane & 31) < 24) bco = bias[lane & 31];

    // ---- stage slab -> XT: task f = dd*34 + w2; 12 f32 loads (ci x kh'), 2x ds_write_b128
    const float* xb = x + (size_t)n*1572864 + h0*128 + W0;
    {
        int w2 = tid % 34;
        int dd = tid / 34;
        int f  = tid;
        while (f < 1088) {
            const bool ok = (W0 + w2) < 128;
            const int boff = ok ? (dd*16384 + w2) : 0;
            float v0  = xb[boff];            // ci0 kh'0..3
            float v1  = xb[boff + 128];
            float v2  = xb[boff + 256];
            float v3  = xb[boff + 384];
            float v4  = xb[boff + 524288];   // ci1
            float v5  = xb[boff + 524416];
            float v6  = xb[boff + 524544];
            float v7  = xb[boff + 524672];
            float v8  = xb[boff + 1048576];  // ci2
            float v9  = xb[boff + 1048704];
            float v10 = xb[boff + 1048832];
            float v11 = xb[boff + 1048960];
            if (!ok) { v0=v1=v2=v3=v4=v5=v6=v7=v8=v9=v10=v11=0.0f; }
            half8 g0, g1 = {};
            g0[0]=(_Float16)v0; g0[1]=(_Float16)v1; g0[2]=(_Float16)v2;  g0[3]=(_Float16)v3;
            g0[4]=(_Float16)v4; g0[5]=(_Float16)v5; g0[6]=(_Float16)v6;  g0[7]=(_Float16)v7;
            g1[0]=(_Float16)v8; g1[1]=(_Float16)v9; g1[2]=(_Float16)v10; g1[3]=(_Float16)v11;
            char* rowp = (char*)XT + (size_t)(dd*34 + w2)*48;
            *(half8*)(rowp)      = g0;
            *(half8*)(rowp + 16) = g1;       // halfs 12..15 = 0 (K pad)
            f += 512; w2 += 2; dd += 15;
            if (w2 >= 34) { w2 -= 34; dd += 1; }
        }
    }
    __syncthreads();

    // ---- conv + min over depth, both h outputs, shared A-fragments
    const char* xt = (const char*)XT;
    const int lanebase = (lane & 31)*48 + q*16;

    floatx16 macc0, macc1;
    #pragma unroll
    for (int i = 0; i < 16; ++i) { macc0[i] = 3.0e38f; macc1[i] = 3.0e38f; }

    int d0, cnt;
    if (wid < 6) { d0 = wid*4;          cnt = 4; }
    else         { d0 = 24 + (wid-6)*3; cnt = 3; }

    for (int dci = 0; dci < cnt; ++dci) {
        const char* xd = xt + (size_t)(d0 + dci)*1632 + lanebase; // 1632 = 34*48
        floatx16 a0{}, a1{};
        #pragma unroll
        for (int kd = 0; kd < 3; ++kd)
          #pragma unroll
          for (int kw = 0; kw < 3; ++kw) {
            half8 fA = *(const half8*)(xd + kd*1632 + kw*48);
            a0 = __builtin_amdgcn_mfma_f32_32x32x16_f16(fA, Bf0[kd][kw], a0, 0, 0, 0);
            a1 = __builtin_amdgcn_mfma_f32_32x32x16_f16(fA, Bf1[kd][kw], a1, 0, 0, 0);
          }
        #pragma unroll
        for (int i = 0; i < 16; ++i) {
            macc0[i] = fminf(macc0[i], a0[i]);
            macc1[i] = fminf(macc1[i], a1[i]);
        }
    }

    // ---- epilogue per output h (delta = 0,1)
    float* xbuf = (float*)XT;                  // 8*16*64 f32 = 32 KB
    float* vbuf = xbuf + 8192;                 // 32*32 f32
    float* pbuf = xbuf + 9216;                 // 24*33 f32 (padded, conflict-free)

    #pragma unroll
    for (int dlt = 0; dlt < 2; ++dlt) {
        const int h = h0 + dlt;
        __syncthreads();                       // XT/xbuf safe to overwrite
        #pragma unroll
        for (int r = 0; r < 16; ++r)
            xbuf[(wid*16 + r)*64 + lane] = (dlt == 0) ? macc0[r] : macc1[r];
        __syncthreads();

        // cross-wave min + scatter to vbuf[w][co] via probed indices
        #pragma unroll
        for (int rr = 0; rr < 2; ++rr) {
            int r = wid*2 + rr;
            float v = xbuf[r*64 + lane];
            #pragma unroll
            for (int w8 = 1; w8 < 8; ++w8)
                v = fminf(v, xbuf[(w8*16 + r)*64 + lane]);
            vbuf[rr == 0 ? ic0 : ic1] = v;
        }
        __syncthreads();

        // softmax over channels: half-wave = one w, lane&31 = co; result -> pbuf[c][w]
        #pragma unroll
        for (int iter = 0; iter < 2; ++iter) {
            int w = wid*4 + q*2 + iter;        // 0..31
            int c = lane & 31;
            float val = (c < 24) ? (vbuf[w*32 + c] + bco) : -3.0e38f;
            float mx = val;
            mx = fmaxf(mx, __shfl_xor(mx, 16, 64));
            mx = fmaxf(mx, __shfl_xor(mx,  8, 64));
            mx = fmaxf(mx, __shfl_xor(mx,  4, 64));
            mx = fmaxf(mx, __shfl_xor(mx,  2, 64));
            mx = fmaxf(mx, __shfl_xor(mx,  1, 64));
            float p = (c < 24) ? __expf(val - mx) : 0.0f;
            float s = p;
            s += __shfl_xor(s, 16, 64);
            s += __shfl_xor(s,  8, 64);
            s += __shfl_xor(s,  4, 64);
            s += __shfl_xor(s,  2, 64);
            s += __shfl_xor(s,  1, 64);
            if (c < 24) pbuf[c*33 + w] = p / s;
        }
        __syncthreads();

        // contiguous stores: waves 0..5, seg = channel row, 32 consecutive w per seg
        if (wid < 6) {
            #pragma unroll
            for (int iter = 0; iter < 2; ++iter) {
                int seg = wid*4 + q*2 + iter;  // 0..23
                int l = lane & 31;
                int w_out = W0 + l;
                if (w_out < 126)
                    out[(((size_t)n*24 + seg)*126 + h)*126 + w_out] = pbuf[seg*33 + l];
            }
        }
    }
}

extern "C" void kernel_launch(void* const* d_in, const int* in_sizes, int n_in,
                              void* d_out, int out_size, void* d_ws, size_t ws_size,
                              hipStream_t stream) {
    const float* x  = (const float*)d_in[0];
    const float* wt = (const float*)d_in[1];
    const float* bs = (const float*)d_in[2];
    float* out = (float*)d_out;

    hipLaunchKernelGGL(ModelNew_80908593922715_prep, dim3(18), dim3(64), 0, stream,
                       wt, d_ws);
    hipLaunchKernelGGL(ModelNew_80908593922715_kernel, dim3(252, 16), dim3(512), 0, stream,
                       x, bs, d_ws, out);
}

// Round 8
// 366.334 us; speedup vs baseline: 1.7630x; 1.7630x over previous
//
#include <hip/hip_runtime.h>

typedef _Float16 half8 __attribute__((ext_vector_type(8)));
typedef float floatx16 __attribute__((ext_vector_type(16)));

// x[16,3,32,128,128] f32 -> Conv3d(3->24,k=3,VALID) -> +bias -> min over depth -> softmax(co)
// out [16,24,1,126,126] f32
//
// v_mfma_f32_32x32x16_f16: M=32 w, N=32 (24 co), K=16 packed k=ci*4+kh' (12 used).
// One staged slab (4 h-rows) serves TWO output h values (delta=0,1) via two B-tables.
// C/D layout self-calibrated in prep (probe MFMAs -> u16 idx table in ws).
// launch_bounds(512,4): VGPR cap 128 — (512,6) capped at 85 and SPILLED the
// ~124-reg live state to scratch (r5/r7: WRITE_SIZE 464/895 MB for a 24 MB output).

#define WS_IDX_OFF 0      // 2048 B: u16 idx[16][64] = wm*32+cm
#define WS_BF_OFF  2048   // 18432 B: half8 Bf[2][3][3][64]

__global__ void ModelNew_80908593922715_prep(const float* __restrict__ wt,
                                             void* __restrict__ ws)
{
    const int lane = threadIdx.x;            // 0..63
    const int co = lane & 31, q = lane >> 5;
    const int b  = blockIdx.x;               // 0..17 = (delta*9 + kd*3 + kw)
    const int dlt = b / 9;
    const int kd = (b % 9) / 3, kw = b % 3;

    half8 bf;
    #pragma unroll
    for (int j = 0; j < 8; ++j) {
        int k = q*8 + j;                     // k = ci*4 + kh'
        int ci = k >> 2, khp = k & 3;
        int kh = khp - dlt;                  // weight kh tap
        float wv = 0.0f;
        if (co < 24 && ci < 3 && kh >= 0 && kh < 3)
            wv = wt[co*81 + ci*27 + kd*9 + kh*3 + kw];
        bf[j] = (_Float16)wv;
    }
    *(half8*)((char*)ws + WS_BF_OFF + (size_t)(b*64 + lane)*16) = bf;

    if (b == 0) {
        // probe ACTUAL C/D layout: dwp = 16*row(w), dcp = 16*col(co)
        half8 pa, pone;
        #pragma unroll
        for (int j = 0; j < 8; ++j) { pa[j] = (_Float16)(float)co; pone[j] = (_Float16)1.0f; }
        floatx16 dwp{}, dcp{};
        dwp = __builtin_amdgcn_mfma_f32_32x32x16_f16(pa,   pone, dwp, 0, 0, 0);
        dcp = __builtin_amdgcn_mfma_f32_32x32x16_f16(pone, pa,   dcp, 0, 0, 0);
        unsigned short* idx = (unsigned short*)((char*)ws + WS_IDX_OFF);
        #pragma unroll
        for (int r = 0; r < 16; ++r) {
            int wm = (int)(dwp[r] * 0.0625f + 0.5f);
            int cm = (int)(dcp[r] * 0.0625f + 0.5f);
            idx[r*64 + lane] = (unsigned short)(wm*32 + cm);
        }
    }
}

__global__ __launch_bounds__(512, 4)
void ModelNew_80908593922715_kernel(const float* __restrict__ x,
                                    const float* __restrict__ bias,
                                    const void* __restrict__ ws,
                                    float* __restrict__ out)
{
    __shared__ __align__(16) _Float16 XT[26112]; // 1088 rows (dd*34+w2) x 48 B

    const int tid  = threadIdx.x;
    const int lane = tid & 63;
    const int wid  = tid >> 6;
    const int q    = lane >> 5;

    // ---- bijective XCD swizzle over 4032 blocks (8 XCDs x 504)
    const int bid = blockIdx.y * 252 + blockIdx.x;
    const int logical = (bid & 7) * 504 + (bid >> 3);
    const int n  = logical / 252;
    const int lx = logical % 252;
    const int hp = lx >> 2;          // 0..62 -> h0 = 2*hp
    const int wq = lx & 3;
    const int h0 = hp * 2;
    const int W0 = wq * 32;

    // ---- constants from ws (L2-resident)
    const char* wsB = (const char*)ws + WS_BF_OFF;
    half8 Bf0[3][3], Bf1[3][3];
    #pragma unroll
    for (int kd = 0; kd < 3; ++kd)
      #pragma unroll
      for (int kw = 0; kw < 3; ++kw) {
        Bf0[kd][kw] = *(const half8*)(wsB + (size_t)(((0*9 + kd*3+kw)*64) + lane)*16);
        Bf1[kd][kw] = *(const half8*)(wsB + (size_t)(((1*9 + kd*3+kw)*64) + lane)*16);
      }

    const unsigned short* idxT = (const unsigned short*)((const char*)ws + WS_IDX_OFF);
    const unsigned short ic0 = idxT[(wid*2 + 0)*64 + lane];
    const unsigned short ic1 = idxT[(wid*2 + 1)*64 + lane];
    float bco = 0.0f;
    if ((lane & 31) < 24) bco = bias[lane & 31];

    // ---- stage slab -> XT: task f = dd*34 + w2; 12 f32 loads (ci x kh'), 2x ds_write_b128
    const float* xb = x + (size_t)n*1572864 + h0*128 + W0;
    {
        int w2 = tid % 34;
        int dd = tid / 34;
        int f  = tid;
        while (f < 1088) {
            const bool ok = (W0 + w2) < 128;
            const int boff = ok ? (dd*16384 + w2) : 0;
            float v0  = xb[boff];            // ci0 kh'0..3
            float v1  = xb[boff + 128];
            float v2  = xb[boff + 256];
            float v3  = xb[boff + 384];
            float v4  = xb[boff + 524288];   // ci1
            float v5  = xb[boff + 524416];
            float v6  = xb[boff + 524544];
            float v7  = xb[boff + 524672];
            float v8  = xb[boff + 1048576];  // ci2
            float v9  = xb[boff + 1048704];
            float v10 = xb[boff + 1048832];
            float v11 = xb[boff + 1048960];
            if (!ok) { v0=v1=v2=v3=v4=v5=v6=v7=v8=v9=v10=v11=0.0f; }
            half8 g0, g1 = {};
            g0[0]=(_Float16)v0; g0[1]=(_Float16)v1; g0[2]=(_Float16)v2;  g0[3]=(_Float16)v3;
            g0[4]=(_Float16)v4; g0[5]=(_Float16)v5; g0[6]=(_Float16)v6;  g0[7]=(_Float16)v7;
            g1[0]=(_Float16)v8; g1[1]=(_Float16)v9; g1[2]=(_Float16)v10; g1[3]=(_Float16)v11;
            char* rowp = (char*)XT + (size_t)(dd*34 + w2)*48;
            *(half8*)(rowp)      = g0;
            *(half8*)(rowp + 16) = g1;       // halfs 12..15 = 0 (K pad)
            f += 512; w2 += 2; dd += 15;
            if (w2 >= 34) { w2 -= 34; dd += 1; }
        }
    }
    __syncthreads();

    // ---- conv + min over depth, both h outputs, shared A-fragments
    const char* xt = (const char*)XT;
    const int lanebase = (lane & 31)*48 + q*16;

    floatx16 macc0, macc1;
    #pragma unroll
    for (int i = 0; i < 16; ++i) { macc0[i] = 3.0e38f; macc1[i] = 3.0e38f; }

    int d0, cnt;
    if (wid < 6) { d0 = wid*4;          cnt = 4; }
    else         { d0 = 24 + (wid-6)*3; cnt = 3; }

    for (int dci = 0; dci < cnt; ++dci) {
        const char* xd = xt + (size_t)(d0 + dci)*1632 + lanebase; // 1632 = 34*48
        floatx16 a0{}, a1{};
        #pragma unroll
        for (int kd = 0; kd < 3; ++kd)
          #pragma unroll
          for (int kw = 0; kw < 3; ++kw) {
            half8 fA = *(const half8*)(xd + kd*1632 + kw*48);
            a0 = __builtin_amdgcn_mfma_f32_32x32x16_f16(fA, Bf0[kd][kw], a0, 0, 0, 0);
            a1 = __builtin_amdgcn_mfma_f32_32x32x16_f16(fA, Bf1[kd][kw], a1, 0, 0, 0);
          }
        #pragma unroll
        for (int i = 0; i < 16; ++i) {
            macc0[i] = fminf(macc0[i], a0[i]);
            macc1[i] = fminf(macc1[i], a1[i]);
        }
    }

    // ---- epilogue per output h (delta = 0,1)
    float* xbuf = (float*)XT;                  // 8*16*64 f32 = 32 KB
    float* vbuf = xbuf + 8192;                 // 32*32 f32
    float* pbuf = xbuf + 9216;                 // 24*33 f32 (padded, conflict-free)

    #pragma unroll
    for (int dlt = 0; dlt < 2; ++dlt) {
        const int h = h0 + dlt;
        __syncthreads();                       // XT/xbuf safe to overwrite
        #pragma unroll
        for (int r = 0; r < 16; ++r)
            xbuf[(wid*16 + r)*64 + lane] = (dlt == 0) ? macc0[r] : macc1[r];
        __syncthreads();

        // cross-wave min + scatter to vbuf[w][co] via probed indices
        #pragma unroll
        for (int rr = 0; rr < 2; ++rr) {
            int r = wid*2 + rr;
            float v = xbuf[r*64 + lane];
            #pragma unroll
            for (int w8 = 1; w8 < 8; ++w8)
                v = fminf(v, xbuf[(w8*16 + r)*64 + lane]);
            vbuf[rr == 0 ? ic0 : ic1] = v;
        }
        __syncthreads();

        // softmax over channels: half-wave = one w, lane&31 = co; result -> pbuf[c][w]
        #pragma unroll
        for (int iter = 0; iter < 2; ++iter) {
            int w = wid*4 + q*2 + iter;        // 0..31
            int c = lane & 31;
            float val = (c < 24) ? (vbuf[w*32 + c] + bco) : -3.0e38f;
            float mx = val;
            mx = fmaxf(mx, __shfl_xor(mx, 16, 64));
            mx = fmaxf(mx, __shfl_xor(mx,  8, 64));
            mx = fmaxf(mx, __shfl_xor(mx,  4, 64));
            mx = fmaxf(mx, __shfl_xor(mx,  2, 64));
            mx = fmaxf(mx, __shfl_xor(mx,  1, 64));
            float p = (c < 24) ? __expf(val - mx) : 0.0f;
            float s = p;
            s += __shfl_xor(s, 16, 64);
            s += __shfl_xor(s,  8, 64);
            s += __shfl_xor(s,  4, 64);
            s += __shfl_xor(s,  2, 64);
            s += __shfl_xor(s,  1, 64);
            if (c < 24) pbuf[c*33 + w] = p / s;
        }
        __syncthreads();

        // contiguous stores: waves 0..5, seg = channel row, 32 consecutive w per seg
        if (wid < 6) {
            #pragma unroll
            for (int iter = 0; iter < 2; ++iter) {
                int seg = wid*4 + q*2 + iter;  // 0..23
                int l = lane & 31;
                int w_out = W0 + l;
                if (w_out < 126)
                    out[(((size_t)n*24 + seg)*126 + h)*126 + w_out] = pbuf[seg*33 + l];
            }
        }
    }
}

extern "C" void kernel_launch(void* const* d_in, const int* in_sizes, int n_in,
                              void* d_out, int out_size, void* d_ws, size_t ws_size,
                              hipStream_t stream) {
    const float* x  = (const float*)d_in[0];
    const float* wt = (const float*)d_in[1];
    const float* bs = (const float*)d_in[2];
    float* out = (float*)d_out;

    hipLaunchKernelGGL(ModelNew_80908593922715_prep, dim3(18), dim3(64), 0, stream,
                       wt, d_ws);
    hipLaunchKernelGGL(ModelNew_80908593922715_kernel, dim3(252, 16), dim3(512), 0, stream,
                       x, bs, d_ws, out);
}

// Round 9
// 218.643 us; speedup vs baseline: 2.9539x; 1.6755x over previous
//
#include <hip/hip_runtime.h>

typedef _Float16 half8 __attribute__((ext_vector_type(8)));
typedef float floatx16 __attribute__((ext_vector_type(16)));

// x[16,3,32,128,128] f32 -> Conv3d(3->24,k=3,VALID) -> +bias -> min over depth -> softmax(co)
// out [16,24,1,126,126] f32
//
// v_mfma_f32_32x32x16_f16: M=32 w, N=32 (24 co), K=16 packed k=ci*4+kh' (12 used).
// One staged slab (4 h-rows) serves TWO output h values (delta=0,1) via two B-tables.
// C/D layout self-calibrated in prep (probe MFMAs -> u16 idx table in ws).
// 256 threads + launch_bounds(256,3): VGPR cap ~170 >= ~150 live regs (Bf0/Bf1 72 +
// acc 64 + temps). (512,4)=cap 128 and (512,6)=cap 85 both SPILLED -> scratch HBM
// traffic (WRITE_SIZE 356/464/895 MB vs 24 MB output in r8/r5/r7).

#define WS_IDX_OFF 0      // 2048 B: u16 idx[16][64] = wm*32+cm
#define WS_BF_OFF  2048   // 18432 B: half8 Bf[2][3][3][64]

__global__ void ModelNew_80908593922715_prep(const float* __restrict__ wt,
                                             void* __restrict__ ws)
{
    const int lane = threadIdx.x;            // 0..63
    const int co = lane & 31, q = lane >> 5;
    const int b  = blockIdx.x;               // 0..17 = (delta*9 + kd*3 + kw)
    const int dlt = b / 9;
    const int kd = (b % 9) / 3, kw = b % 3;

    half8 bf;
    #pragma unroll
    for (int j = 0; j < 8; ++j) {
        int k = q*8 + j;                     // k = ci*4 + kh'
        int ci = k >> 2, khp = k & 3;
        int kh = khp - dlt;                  // weight kh tap
        float wv = 0.0f;
        if (co < 24 && ci < 3 && kh >= 0 && kh < 3)
            wv = wt[co*81 + ci*27 + kd*9 + kh*3 + kw];
        bf[j] = (_Float16)wv;
    }
    *(half8*)((char*)ws + WS_BF_OFF + (size_t)(b*64 + lane)*16) = bf;

    if (b == 0) {
        // probe ACTUAL C/D layout: dwp = 16*row(w), dcp = 16*col(co)
        half8 pa, pone;
        #pragma unroll
        for (int j = 0; j < 8; ++j) { pa[j] = (_Float16)(float)co; pone[j] = (_Float16)1.0f; }
        floatx16 dwp{}, dcp{};
        dwp = __builtin_amdgcn_mfma_f32_32x32x16_f16(pa,   pone, dwp, 0, 0, 0);
        dcp = __builtin_amdgcn_mfma_f32_32x32x16_f16(pone, pa,   dcp, 0, 0, 0);
        unsigned short* idx = (unsigned short*)((char*)ws + WS_IDX_OFF);
        #pragma unroll
        for (int r = 0; r < 16; ++r) {
            int wm = (int)(dwp[r] * 0.0625f + 0.5f);
            int cm = (int)(dcp[r] * 0.0625f + 0.5f);
            idx[r*64 + lane] = (unsigned short)(wm*32 + cm);
        }
    }
}

__global__ __launch_bounds__(256, 3)
void ModelNew_80908593922715_kernel(const float* __restrict__ x,
                                    const float* __restrict__ bias,
                                    const void* __restrict__ ws,
                                    float* __restrict__ out)
{
    __shared__ __align__(16) _Float16 XT[26112]; // 1088 rows (dd*34+w2) x 48 B

    const int tid  = threadIdx.x;
    const int lane = tid & 63;
    const int wid  = tid >> 6;               // 0..3
    const int q    = lane >> 5;

    // ---- bijective XCD swizzle over 4032 blocks (8 XCDs x 504)
    const int bid = blockIdx.y * 252 + blockIdx.x;
    const int logical = (bid & 7) * 504 + (bid >> 3);
    const int n  = logical / 252;
    const int lx = logical % 252;
    const int hp = lx >> 2;          // 0..62 -> h0 = 2*hp
    const int wq = lx & 3;
    const int h0 = hp * 2;
    const int W0 = wq * 32;

    // ---- constants from ws (L2-resident)
    const char* wsB = (const char*)ws + WS_BF_OFF;
    half8 Bf0[3][3], Bf1[3][3];
    #pragma unroll
    for (int kd = 0; kd < 3; ++kd)
      #pragma unroll
      for (int kw = 0; kw < 3; ++kw) {
        Bf0[kd][kw] = *(const half8*)(wsB + (size_t)(((0*9 + kd*3+kw)*64) + lane)*16);
        Bf1[kd][kw] = *(const half8*)(wsB + (size_t)(((1*9 + kd*3+kw)*64) + lane)*16);
      }

    const unsigned short* idxT = (const unsigned short*)((const char*)ws + WS_IDX_OFF);
    unsigned short ic[4];
    #pragma unroll
    for (int rr = 0; rr < 4; ++rr)
        ic[rr] = idxT[(wid*4 + rr)*64 + lane];
    float bco = 0.0f;
    if ((lane & 31) < 24) bco = bias[lane & 31];

    // ---- stage slab -> XT: task f = dd*34 + w2; 12 f32 loads (ci x kh'), 2x ds_write_b128
    const float* xb = x + (size_t)n*1572864 + h0*128 + W0;
    {
        int w2 = tid % 34;
        int dd = tid / 34;
        int f  = tid;
        while (f < 1088) {
            const bool ok = (W0 + w2) < 128;
            const int boff = ok ? (dd*16384 + w2) : 0;
            float v0  = xb[boff];            // ci0 kh'0..3
            float v1  = xb[boff + 128];
            float v2  = xb[boff + 256];
            float v3  = xb[boff + 384];
            float v4  = xb[boff + 524288];   // ci1
            float v5  = xb[boff + 524416];
            float v6  = xb[boff + 524544];
            float v7  = xb[boff + 524672];
            float v8  = xb[boff + 1048576];  // ci2
            float v9  = xb[boff + 1048704];
            float v10 = xb[boff + 1048832];
            float v11 = xb[boff + 1048960];
            if (!ok) { v0=v1=v2=v3=v4=v5=v6=v7=v8=v9=v10=v11=0.0f; }
            half8 g0, g1 = {};
            g0[0]=(_Float16)v0; g0[1]=(_Float16)v1; g0[2]=(_Float16)v2;  g0[3]=(_Float16)v3;
            g0[4]=(_Float16)v4; g0[5]=(_Float16)v5; g0[6]=(_Float16)v6;  g0[7]=(_Float16)v7;
            g1[0]=(_Float16)v8; g1[1]=(_Float16)v9; g1[2]=(_Float16)v10; g1[3]=(_Float16)v11;
            char* rowp = (char*)XT + (size_t)(dd*34 + w2)*48;
            *(half8*)(rowp)      = g0;
            *(half8*)(rowp + 16) = g1;       // halfs 12..15 = 0 (K pad)
            f += 256; w2 += 18; dd += 7;     // 256 = 7*34 + 18
            if (w2 >= 34) { w2 -= 34; dd += 1; }
        }
    }
    __syncthreads();

    // ---- conv + min over depth, both h outputs, shared A-fragments
    const char* xt = (const char*)XT;
    const int lanebase = (lane & 31)*48 + q*16;

    floatx16 macc0, macc1;
    #pragma unroll
    for (int i = 0; i < 16; ++i) { macc0[i] = 3.0e38f; macc1[i] = 3.0e38f; }

    int d0, cnt;
    if (wid < 2) { d0 = wid*8;          cnt = 8; }
    else         { d0 = 16 + (wid-2)*7; cnt = 7; }

    for (int dci = 0; dci < cnt; ++dci) {
        const char* xd = xt + (size_t)(d0 + dci)*1632 + lanebase; // 1632 = 34*48
        floatx16 a0{}, a1{};
        #pragma unroll
        for (int kd = 0; kd < 3; ++kd)
          #pragma unroll
          for (int kw = 0; kw < 3; ++kw) {
            half8 fA = *(const half8*)(xd + kd*1632 + kw*48);
            a0 = __builtin_amdgcn_mfma_f32_32x32x16_f16(fA, Bf0[kd][kw], a0, 0, 0, 0);
            a1 = __builtin_amdgcn_mfma_f32_32x32x16_f16(fA, Bf1[kd][kw], a1, 0, 0, 0);
          }
        #pragma unroll
        for (int i = 0; i < 16; ++i) {
            macc0[i] = fminf(macc0[i], a0[i]);
            macc1[i] = fminf(macc1[i], a1[i]);
        }
    }

    // ---- epilogue per output h (delta = 0,1)
    float* xbuf = (float*)XT;                  // 4 waves * 16 regs * 64 lanes = 16 KB
    float* vbuf = xbuf + 4096;                 // 32*32 f32
    float* pbuf = xbuf + 5120;                 // 24*33 f32 (padded, conflict-free)

    #pragma unroll
    for (int dlt = 0; dlt < 2; ++dlt) {
        const int h = h0 + dlt;
        __syncthreads();                       // XT/xbuf safe to overwrite
        #pragma unroll
        for (int r = 0; r < 16; ++r)
            xbuf[(wid*16 + r)*64 + lane] = (dlt == 0) ? macc0[r] : macc1[r];
        __syncthreads();

        // cross-wave min + scatter to vbuf[w][co] via probed indices
        #pragma unroll
        for (int rr = 0; rr < 4; ++rr) {
            int r = wid*4 + rr;
            float v = xbuf[r*64 + lane];
            #pragma unroll
            for (int w4 = 1; w4 < 4; ++w4)
                v = fminf(v, xbuf[(w4*16 + r)*64 + lane]);
            vbuf[ic[rr]] = v;
        }
        __syncthreads();

        // softmax over channels: each half-wave handles 4 w rows; lane&31 = co
        #pragma unroll
        for (int iter = 0; iter < 4; ++iter) {
            int w = (wid*2 + q)*4 + iter;      // 0..31
            int c = lane & 31;
            float val = (c < 24) ? (vbuf[w*32 + c] + bco) : -3.0e38f;
            float mx = val;
            mx = fmaxf(mx, __shfl_xor(mx, 16, 64));
            mx = fmaxf(mx, __shfl_xor(mx,  8, 64));
            mx = fmaxf(mx, __shfl_xor(mx,  4, 64));
            mx = fmaxf(mx, __shfl_xor(mx,  2, 64));
            mx = fmaxf(mx, __shfl_xor(mx,  1, 64));
            float p = (c < 24) ? __expf(val - mx) : 0.0f;
            float s = p;
            s += __shfl_xor(s, 16, 64);
            s += __shfl_xor(s,  8, 64);
            s += __shfl_xor(s,  4, 64);
            s += __shfl_xor(s,  2, 64);
            s += __shfl_xor(s,  1, 64);
            if (c < 24) pbuf[c*33 + w] = p / s;
        }
        __syncthreads();

        // contiguous stores: waves 0..2, seg = channel row, 32 consecutive w per seg
        if (wid < 3) {
            #pragma unroll
            for (int iter = 0; iter < 4; ++iter) {
                int seg = wid*8 + q*4 + iter;  // 0..23
                int l = lane & 31;
                int w_out = W0 + l;
                if (w_out < 126)
                    out[(((size_t)n*24 + seg)*126 + h)*126 + w_out] = pbuf[seg*33 + l];
            }
        }
    }
}

extern "C" void kernel_launch(void* const* d_in, const int* in_sizes, int n_in,
                              void* d_out, int out_size, void* d_ws, size_t ws_size,
                              hipStream_t stream) {
    const float* x  = (const float*)d_in[0];
    const float* wt = (const float*)d_in[1];
    const float* bs = (const float*)d_in[2];
    float* out = (float*)d_out;

    hipLaunchKernelGGL(ModelNew_80908593922715_prep, dim3(18), dim3(64), 0, stream,
                       wt, d_ws);
    hipLaunchKernelGGL(ModelNew_80908593922715_kernel, dim3(252, 16), dim3(256), 0, stream,
                       x, bs, d_ws, out);
}